// Round 1
// baseline (1265.165 us; speedup 1.0000x reference)
//
#include <hip/hip_runtime.h>
#include <math.h>

namespace {

constexpr int NN  = 50000;
constexpr int CC  = 128;
constexpr int H0n = 256;
constexpr int H1n = 128;
constexpr int EMn = 1000000;
constexpr int ESn = 200000;
constexpr int TE  = 16;   // edges per block in MLP kernel

__device__ __forceinline__ unsigned fmap(float f) {
  unsigned u = __float_as_uint(f);
  return (u & 0x80000000u) ? ~u : (u | 0x80000000u);
}
__device__ __forceinline__ float funmap(unsigned u) {
  unsigned v = (u & 0x80000000u) ? (u & 0x7FFFFFFFu) : ~u;
  return __uint_as_float(v);
}
__device__ __forceinline__ float softplusf(float x) {
  return (x > 20.f) ? x : log1pf(expf(x));
}
__device__ __forceinline__ float wred(float v) {
#pragma unroll
  for (int o = 32; o; o >>= 1) v += __shfl_xor(v, o, 64);
  return v;
}
__device__ __forceinline__ void fma4(float (&a)[4], float s, const float4& w) {
  a[0] += s * w.x; a[1] += s * w.y; a[2] += s * w.z; a[3] += s * w.w;
}

// ---- K0: init scratch ----
__global__ void k_init(int* __restrict__ pidx, unsigned* __restrict__ smax,
                       float* __restrict__ den, float* __restrict__ num,
                       float* __restrict__ cnt) {
  int i = blockIdx.x * blockDim.x + threadIdx.x;
  if (i < NN) pidx[i] = -1;
  if (i <= NN) { smax[i] = 0u; den[i] = 0.f; num[i] = 0.f; cnt[i] = 0.f; }
}

// ---- K1: inverse row norms of nodes_latent (one wave per row) ----
__global__ void k_norm(const float* __restrict__ nodes, float* __restrict__ invn) {
  int row = blockIdx.x * 4 + (threadIdx.x >> 6);
  int l = threadIdx.x & 63;
  if (row >= NN) return;
  const float* r = nodes + (size_t)row * CC;
  float a = r[l], b = r[l + 64];
  float s = wred(a * a + b * b);
  if (l == 0) invn[row] = 1.0f / fmaxf(sqrtf(s), 1e-8f);
}

// ---- K2: partner_index scatter-max ----
__global__ void k_partner(const int* __restrict__ ss, const int* __restrict__ sd,
                          int* __restrict__ pidx) {
  int i = blockIdx.x * blockDim.x + threadIdx.x;
  if (i >= 2 * ESn) return;
  int partner = (i < ESn) ? sd[i] : ss[i - ESn];
  atomicMax(&pidx[partner], i);
}

// ---- K3: per message edge: q, cos, segment max (one wave per edge) ----
__global__ void k_cos(const float* __restrict__ nodes, const float* __restrict__ invn,
                      const int* __restrict__ ss, const int* __restrict__ sd,
                      const int* __restrict__ ms, const int* __restrict__ md,
                      const int* __restrict__ pidx, int* __restrict__ qarr,
                      float* __restrict__ cosar, unsigned* __restrict__ smax) {
  int e = blockIdx.x * 4 + (threadIdx.x >> 6);
  int l = threadIdx.x & 63;
  if (e >= EMn) return;
  int d = md[e];
  int pi = pidx[d];
  if (pi < 0) { if (l == 0) qarr[e] = -1; return; }
  int q = (pi < ESn) ? ss[pi] : sd[pi - ESn];
  int s = ms[e];
  const float* rq = nodes + (size_t)q * CC;
  const float* rs = nodes + (size_t)s * CC;
  float dot = wred(rq[l] * rs[l] + rq[l + 64] * rs[l + 64]);
  if (l == 0) {
    float cv = dot * invn[q] * invn[s];
    qarr[e] = q;
    cosar[e] = cv;
    atomicMax(&smax[q], fmap(10.0f * cv));
  }
}

// ---- K4: segmented sums of exp / exp*cos / count ----
__global__ void k_seg(const int* __restrict__ qarr, const float* __restrict__ cosar,
                      const unsigned* __restrict__ smax, float* __restrict__ den,
                      float* __restrict__ num, float* __restrict__ cnt) {
  int e = blockIdx.x * blockDim.x + threadIdx.x;
  if (e >= EMn) return;
  int q = qarr[e];
  if (q < 0) return;
  float cv = cosar[e];
  float m = funmap(smax[q]);
  float w = expf(10.0f * cv - m);
  atomicAdd(&den[q], w);
  atomicAdd(&num[q], w * cv);
  atomicAdd(&cnt[q], 1.0f);
}

// ---- K5: cong_node ----
__global__ void k_cong(const float* __restrict__ den, const float* __restrict__ num,
                       const float* __restrict__ cnt, float* __restrict__ cong) {
  int n = blockIdx.x * blockDim.x + threadIdx.x;
  if (n >= NN) return;
  float c = cnt[n];
  cong[n] = (c > 0.f) ? (num[n] / den[n]) / c : 0.f;
}

// ---- K6: fused main MLP + heads, 16 edges per 256-thread block ----
__global__ void k_mlp(const float* __restrict__ nodes, const float* __restrict__ nbrs,
                      const int* __restrict__ ssrc, const int* __restrict__ sdst,
                      const float* __restrict__ cong,
                      const float* __restrict__ W0, const float* __restrict__ b0,
                      const float* __restrict__ g0, const float* __restrict__ be0,
                      const float* __restrict__ W1, const float* __restrict__ b1,
                      const float* __restrict__ g1, const float* __restrict__ be1,
                      const float* __restrict__ Wp, const float* __restrict__ bp,
                      const float* __restrict__ Ww, const float* __restrict__ bw,
                      const float* __restrict__ sscale, const float* __restrict__ sshift,
                      const float* __restrict__ craw, float* __restrict__ out) {
  __shared__ float comb[TE][260];   // combined, then reused for h (rows padded: 260*4B = 65*16B)
  __shared__ float efb[TE][132];    // ef pre-LN
  __shared__ int esrc[TE], edst[TE];

  int t = threadIdx.x;
  int s0 = blockIdx.x * TE;
  if (t < TE) { esrc[t] = ssrc[s0 + t]; edst[t] = sdst[s0 + t]; }
  __syncthreads();

  // load combined = [a | m]
  {
    int c = t & 127;
    int half = t >> 7;
#pragma unroll
    for (int r = 0; r < 8; r++) {
      int e = r * 2 + half;
      const float* rs = nodes + (size_t)esrc[e] * CC;
      const float* rd = nodes + (size_t)edst[e] * CC;
      float x = rs[c], y = rd[c];
      comb[e][c] = x + y;
      comb[e][CC + c] = x * y;
    }
  }
  __syncthreads();

  int w = t >> 6;   // wave -> edges 4w..4w+3
  int l = t & 63;   // lane

  // GEMM1: h[e][4l..4l+3] = combined @ W0 + b0
  float acc[4][4];
  {
    float4 bv = *(const float4*)&b0[4 * l];
#pragma unroll
    for (int e = 0; e < 4; e++) { acc[e][0] = bv.x; acc[e][1] = bv.y; acc[e][2] = bv.z; acc[e][3] = bv.w; }
    for (int i0 = 0; i0 < 2 * CC; i0 += 4) {
      float4 cv0 = *(const float4*)&comb[4 * w + 0][i0];
      float4 cv1 = *(const float4*)&comb[4 * w + 1][i0];
      float4 cv2 = *(const float4*)&comb[4 * w + 2][i0];
      float4 cv3 = *(const float4*)&comb[4 * w + 3][i0];
      float4 wv0 = *(const float4*)&W0[(size_t)(i0 + 0) * H0n + 4 * l];
      float4 wv1 = *(const float4*)&W0[(size_t)(i0 + 1) * H0n + 4 * l];
      float4 wv2 = *(const float4*)&W0[(size_t)(i0 + 2) * H0n + 4 * l];
      float4 wv3 = *(const float4*)&W0[(size_t)(i0 + 3) * H0n + 4 * l];
      fma4(acc[0], cv0.x, wv0); fma4(acc[0], cv0.y, wv1); fma4(acc[0], cv0.z, wv2); fma4(acc[0], cv0.w, wv3);
      fma4(acc[1], cv1.x, wv0); fma4(acc[1], cv1.y, wv1); fma4(acc[1], cv1.z, wv2); fma4(acc[1], cv1.w, wv3);
      fma4(acc[2], cv2.x, wv0); fma4(acc[2], cv2.y, wv1); fma4(acc[2], cv2.z, wv2); fma4(acc[2], cv2.w, wv3);
      fma4(acc[3], cv3.x, wv0); fma4(acc[3], cv3.y, wv1); fma4(acc[3], cv3.z, wv2); fma4(acc[3], cv3.w, wv3);
    }
  }
  __syncthreads();
  // store h into comb (reuse)
#pragma unroll
  for (int e = 0; e < 4; e++) {
    float4 hv = make_float4(acc[e][0], acc[e][1], acc[e][2], acc[e][3]);
    *(float4*)&comb[4 * w + e][4 * l] = hv;
  }
  __syncthreads();

  // LN1 + relu, in place (wave w handles its 4 edges)
#pragma unroll
  for (int er = 0; er < 4; er++) {
    int e = 4 * w + er;
    float x0 = comb[e][l], x1 = comb[e][l + 64], x2 = comb[e][l + 128], x3 = comb[e][l + 192];
    float s = wred(x0 + x1 + x2 + x3);
    float sq = wred(x0 * x0 + x1 * x1 + x2 * x2 + x3 * x3);
    float mu = s * (1.0f / H0n);
    float var = sq * (1.0f / H0n) - mu * mu;
    float rstd = rsqrtf(var + 1e-5f);
    comb[e][l]       = fmaxf((x0 - mu) * rstd * g0[l]       + be0[l],       0.f);
    comb[e][l + 64]  = fmaxf((x1 - mu) * rstd * g0[l + 64]  + be0[l + 64],  0.f);
    comb[e][l + 128] = fmaxf((x2 - mu) * rstd * g0[l + 128] + be0[l + 128], 0.f);
    comb[e][l + 192] = fmaxf((x3 - mu) * rstd * g0[l + 192] + be0[l + 192], 0.f);
  }
  __syncthreads();

  // GEMM2: ef[e][2l..2l+1] = h_ln @ W1 + b1
  float2 acc2[4];
  {
    float2 bv = *(const float2*)&b1[2 * l];
#pragma unroll
    for (int e = 0; e < 4; e++) acc2[e] = bv;
    for (int i0 = 0; i0 < H0n; i0 += 4) {
      float4 cv0 = *(const float4*)&comb[4 * w + 0][i0];
      float4 cv1 = *(const float4*)&comb[4 * w + 1][i0];
      float4 cv2 = *(const float4*)&comb[4 * w + 2][i0];
      float4 cv3 = *(const float4*)&comb[4 * w + 3][i0];
      float2 wv0 = *(const float2*)&W1[(size_t)(i0 + 0) * H1n + 2 * l];
      float2 wv1 = *(const float2*)&W1[(size_t)(i0 + 1) * H1n + 2 * l];
      float2 wv2 = *(const float2*)&W1[(size_t)(i0 + 2) * H1n + 2 * l];
      float2 wv3 = *(const float2*)&W1[(size_t)(i0 + 3) * H1n + 2 * l];
      acc2[0].x += cv0.x * wv0.x + cv0.y * wv1.x + cv0.z * wv2.x + cv0.w * wv3.x;
      acc2[0].y += cv0.x * wv0.y + cv0.y * wv1.y + cv0.z * wv2.y + cv0.w * wv3.y;
      acc2[1].x += cv1.x * wv0.x + cv1.y * wv1.x + cv1.z * wv2.x + cv1.w * wv3.x;
      acc2[1].y += cv1.x * wv0.y + cv1.y * wv1.y + cv1.z * wv2.y + cv1.w * wv3.y;
      acc2[2].x += cv2.x * wv0.x + cv2.y * wv1.x + cv2.z * wv2.x + cv2.w * wv3.x;
      acc2[2].y += cv2.x * wv0.y + cv2.y * wv1.y + cv2.z * wv2.y + cv2.w * wv3.y;
      acc2[3].x += cv3.x * wv0.x + cv3.y * wv1.x + cv3.z * wv2.x + cv3.w * wv3.x;
      acc2[3].y += cv3.x * wv0.y + cv3.y * wv1.y + cv3.z * wv2.y + cv3.w * wv3.y;
    }
  }
#pragma unroll
  for (int e = 0; e < 4; e++) *(float2*)&efb[4 * w + e][2 * l] = acc2[e];
  __syncthreads();

  // coeff (SoftplusSimplex) — computed redundantly per thread, cheap
  float u0 = softplusf(craw[0]), u1 = softplusf(craw[1]), u2 = softplusf(craw[2]);
  float usum = u0 + u1 + u2;
  float c0 = u0 / usum, c1 = u1 / usum, c2 = u2 / usum;
  float sc = sscale[0], sh = sshift[0];

  // LN2 + relu + heads
#pragma unroll
  for (int er = 0; er < 4; er++) {
    int e = 4 * w + er;
    float x0 = efb[e][l], x1 = efb[e][l + 64];
    float s = wred(x0 + x1);
    float sq = wred(x0 * x0 + x1 * x1);
    float mu = s * (1.0f / H1n);
    float var = sq * (1.0f / H1n) - mu * mu;
    float rstd = rsqrtf(var + 1e-5f);
    float e0 = fmaxf((x0 - mu) * rstd * g1[l]      + be1[l],      0.f);
    float e1 = fmaxf((x1 - mu) * rstd * g1[l + 64] + be1[l + 64], 0.f);
    const float* ns = nbrs + (size_t)esrc[e] * CC;
    const float* nd = nbrs + (size_t)edst[e] * CC;
    float nsim = wred(ns[l] * nd[l] + ns[l + 64] * nd[l + 64]);
    float pd   = wred(e0 * Wp[l] + e1 * Wp[l + 64]);
    float wsum = wred(e0 * Ww[l] + e1 * Ww[l + 64]);
    if (l == 0) {
      int sidx = s0 + e;
      float P_dec  = pd + bp[0];
      float P_nbr  = sc * (nsim + sh);
      float exist  = cong[esrc[e]] + cong[edst[e]];
      float P_cong = sc * (exist + sh);
      out[3 * sidx + 0] = c0 * P_dec;
      out[3 * sidx + 1] = c1 * P_nbr;
      out[3 * sidx + 2] = c2 * P_cong;
      out[3 * ESn + sidx] = fmaxf(wsum + nsim * Ww[H1n] + bw[0], 0.f);
    }
  }
  if (blockIdx.x == 0 && t == 0) {
    out[4 * ESn + 0] = c0; out[4 * ESn + 1] = c1; out[4 * ESn + 2] = c2;
  }
}

} // namespace

extern "C" void kernel_launch(void* const* d_in, const int* in_sizes, int n_in,
                              void* d_out, int out_size, void* d_ws, size_t ws_size,
                              hipStream_t stream) {
  (void)in_sizes; (void)n_in; (void)out_size; (void)ws_size;
  const float* nodes  = (const float*)d_in[0];
  const float* nbrs   = (const float*)d_in[1];
  const int* sup_src  = (const int*)d_in[2];
  const int* sup_dst  = (const int*)d_in[3];
  const int* msg_src  = (const int*)d_in[4];
  const int* msg_dst  = (const int*)d_in[5];
  // d_in[6] message_edgestr: dead (only feeds discarded `strength`)
  const float* W0  = (const float*)d_in[7];
  const float* b0  = (const float*)d_in[8];
  const float* g0  = (const float*)d_in[9];
  const float* be0 = (const float*)d_in[10];
  const float* W1  = (const float*)d_in[11];
  const float* b1  = (const float*)d_in[12];
  const float* g1  = (const float*)d_in[13];
  const float* be1 = (const float*)d_in[14];
  const float* Wp  = (const float*)d_in[15];
  const float* bp  = (const float*)d_in[16];
  const float* Ww  = (const float*)d_in[17];
  const float* bw  = (const float*)d_in[18];
  const float* sscale = (const float*)d_in[19];
  const float* sshift = (const float*)d_in[20];
  const float* craw   = (const float*)d_in[21];
  // d_in[22..27] mm_*: dead (MonotoneMap output is discarded)
  float* out = (float*)d_out;

  char* p = (char*)d_ws;
  auto take = [&](size_t bytes) -> char* {
    char* r = p; p += (bytes + 255) & ~(size_t)255; return r;
  };
  float*    invn  = (float*)take((size_t)NN * 4);
  int*      pidx  = (int*)take((size_t)NN * 4);
  int*      qarr  = (int*)take((size_t)EMn * 4);
  float*    cosar = (float*)take((size_t)EMn * 4);
  unsigned* smax  = (unsigned*)take((size_t)(NN + 1) * 4);
  float*    den   = (float*)take((size_t)(NN + 1) * 4);
  float*    num   = (float*)take((size_t)(NN + 1) * 4);
  float*    cnt   = (float*)take((size_t)(NN + 1) * 4);
  float*    cong  = (float*)take((size_t)NN * 4);

  k_init<<<(NN + 1 + 255) / 256, 256, 0, stream>>>(pidx, smax, den, num, cnt);
  k_norm<<<(NN + 3) / 4, 256, 0, stream>>>(nodes, invn);
  k_partner<<<(2 * ESn + 255) / 256, 256, 0, stream>>>(sup_src, sup_dst, pidx);
  k_cos<<<EMn / 4, 256, 0, stream>>>(nodes, invn, sup_src, sup_dst, msg_src, msg_dst,
                                     pidx, qarr, cosar, smax);
  k_seg<<<(EMn + 255) / 256, 256, 0, stream>>>(qarr, cosar, smax, den, num, cnt);
  k_cong<<<(NN + 255) / 256, 256, 0, stream>>>(den, num, cnt, cong);
  k_mlp<<<ESn / TE, 256, 0, stream>>>(nodes, nbrs, sup_src, sup_dst, cong,
                                      W0, b0, g0, be0, W1, b1, g1, be1,
                                      Wp, bp, Ww, bw, sscale, sshift, craw, out);
}

// Round 2
// 596.188 us; speedup vs baseline: 2.1221x; 2.1221x over previous
//
#include <hip/hip_runtime.h>
#include <math.h>

namespace {

constexpr int NN  = 50000;
constexpr int CC  = 128;
constexpr int EMn = 1000000;
constexpr int ESn = 200000;

using f32x4  = __attribute__((ext_vector_type(4))) float;
using short8 = __attribute__((ext_vector_type(8))) short;

__device__ __forceinline__ ushort f2bf(float f) {
  unsigned u = __float_as_uint(f);
  return (ushort)((u + 0x7fffu + ((u >> 16) & 1u)) >> 16);   // RNE
}
__device__ __forceinline__ float softplusf(float x) {
  return (x > 20.f) ? x : log1pf(expf(x));
}
__device__ __forceinline__ float wred64(float v) {
#pragma unroll
  for (int o = 32; o; o >>= 1) v += __shfl_xor(v, o, 64);
  return v;
}

// ---- K0: init scratch ----
__global__ void k_init(int* __restrict__ pidx, float* __restrict__ den,
                       float* __restrict__ num, float* __restrict__ cnt) {
  int i = blockIdx.x * blockDim.x + threadIdx.x;
  if (i < NN) { pidx[i] = -1; den[i] = 0.f; num[i] = 0.f; cnt[i] = 0.f; }
}

// ---- K_prep: transpose + bf16-convert W0 [256x256] and W1 [256x128] ----
__global__ void k_prep(const float* __restrict__ W0, const float* __restrict__ W1,
                       ushort* __restrict__ w0t, ushort* __restrict__ w1t) {
  __shared__ float tl[32][33];
  int b = blockIdx.x;
  const float* src; ushort* dst; int N, tk, tn;
  if (b < 64) { src = W0; dst = w0t; N = 256; tk = b >> 3; tn = b & 7; }
  else        { b -= 64; src = W1; dst = w1t; N = 128; tk = b >> 2; tn = b & 3; }
  int tx = threadIdx.x & 31, ty = threadIdx.x >> 5;
#pragma unroll
  for (int yy = 0; yy < 32; yy += 8)
    tl[ty + yy][tx] = src[(size_t)(tk * 32 + ty + yy) * N + tn * 32 + tx];
  __syncthreads();
#pragma unroll
  for (int yy = 0; yy < 32; yy += 8)
    dst[(size_t)(tn * 32 + ty + yy) * 256 + tk * 32 + tx] = f2bf(tl[tx][ty + yy]);
}

// ---- K1: inverse row norms (one wave per row) ----
__global__ void k_norm(const float* __restrict__ nodes, float* __restrict__ invn) {
  int row = blockIdx.x * 4 + (threadIdx.x >> 6);
  int l = threadIdx.x & 63;
  if (row >= NN) return;
  const float* r = nodes + (size_t)row * CC;
  float a = r[l], b = r[l + 64];
  float s = wred64(a * a + b * b);
  if (l == 0) invn[row] = 1.0f / fmaxf(sqrtf(s), 1e-8f);
}

// ---- K2: partner_index scatter-max ----
__global__ void k_partner(const int* __restrict__ ss, const int* __restrict__ sd,
                          int* __restrict__ pidx) {
  int i = blockIdx.x * blockDim.x + threadIdx.x;
  if (i >= 2 * ESn) return;
  int partner = (i < ESn) ? sd[i] : ss[i - ESn];
  atomicMax(&pidx[partner], i);
}

// ---- K3: fused cos + segmented sums (16 lanes per message edge) ----
// exp(score - segmax) softmax is shift-invariant -> skip the max pass entirely.
__global__ void k_cos16(const float* __restrict__ nodes, const float* __restrict__ invn,
                        const int* __restrict__ ss, const int* __restrict__ sd,
                        const int* __restrict__ ms, const int* __restrict__ md,
                        const int* __restrict__ pidx, float* __restrict__ den,
                        float* __restrict__ num, float* __restrict__ cnt) {
  int t = threadIdx.x;
  int e = blockIdx.x * 16 + (t >> 4);
  int li = t & 15;
  int d = md[e];
  int pi = pidx[d];
  if (pi < 0) return;                       // uniform per 16-lane group
  int q = (pi < ESn) ? ss[pi] : sd[pi - ESn];
  int s = ms[e];
  const float4* rq = (const float4*)(nodes + (size_t)q * CC) + li * 2;
  const float4* rs = (const float4*)(nodes + (size_t)s * CC) + li * 2;
  float4 a0 = rq[0], b0 = rs[0], a1 = rq[1], b1 = rs[1];
  float dot = a0.x * b0.x + a0.y * b0.y + a0.z * b0.z + a0.w * b0.w
            + a1.x * b1.x + a1.y * b1.y + a1.z * b1.z + a1.w * b1.w;
#pragma unroll
  for (int off = 1; off < 16; off <<= 1) dot += __shfl_xor(dot, off, 64);
  if (li == 0) {
    float cv = dot * invn[q] * invn[s];
    float wv = expf(10.0f * cv);
    atomicAdd(&den[q], wv);
    atomicAdd(&num[q], wv * cv);
    atomicAdd(&cnt[q], 1.0f);
  }
}

// ---- K5: cong_node ----
__global__ void k_cong(const float* __restrict__ den, const float* __restrict__ num,
                       const float* __restrict__ cnt, float* __restrict__ cong) {
  int n = blockIdx.x * blockDim.x + threadIdx.x;
  if (n >= NN) return;
  float c = cnt[n];
  cong[n] = (c > 0.f) ? (num[n] / den[n]) / c : 0.f;
}

// ---- K6: fused MFMA MLP + heads. 64 edges/block, 4 waves, zero barriers ----
__global__ __launch_bounds__(256) void k_mlp(
    const float* __restrict__ nodes, const float* __restrict__ nbrs,
    const int* __restrict__ ssrc, const int* __restrict__ sdst,
    const float* __restrict__ cong,
    const ushort* __restrict__ w0t, const ushort* __restrict__ w1t,
    const float* __restrict__ b0, const float* __restrict__ g0, const float* __restrict__ be0,
    const float* __restrict__ b1, const float* __restrict__ g1, const float* __restrict__ be1,
    const float* __restrict__ Wp, const float* __restrict__ bp,
    const float* __restrict__ Ww, const float* __restrict__ bw,
    const float* __restrict__ sscale, const float* __restrict__ sshift,
    const float* __restrict__ craw, float* __restrict__ out) {
  __shared__ ushort tile[64][256];          // combined (bf16, XOR-swizzled), reused for h_ln

  const int t = threadIdx.x;
  const int w = t >> 6, l = t & 63;
  const int li = l & 15, hi = l >> 4;
  const int s0 = blockIdx.x * 64;

  // ---- stage combined = [a | m], bf16, swizzled. Each wave stages its own 16 rows ----
  {
    int r = w * 16 + (l >> 2);              // tile row
    int q = l & 3;                          // col quarter (32 cols, both halves)
    int es = ssrc[s0 + r], ed = sdst[s0 + r];
    const float4* xs = (const float4*)(nodes + (size_t)es * CC) + q * 8;
    const float4* ys = (const float4*)(nodes + (size_t)ed * CC) + q * 8;
    int sw = (r & 7) << 3;
#pragma unroll
    for (int i = 0; i < 8; i++) {
      float4 x = xs[i], y = ys[i];
      int ca = (q * 32 + i * 4) ^ sw;
      int cm = (128 + q * 32 + i * 4) ^ sw;
      *(ushort4*)&tile[r][ca] =
          make_ushort4(f2bf(x.x + y.x), f2bf(x.y + y.y), f2bf(x.z + y.z), f2bf(x.w + y.w));
      *(ushort4*)&tile[r][cm] =
          make_ushort4(f2bf(x.x * y.x), f2bf(x.y * y.y), f2bf(x.z * y.z), f2bf(x.w * y.w));
    }
  }

  const int rA = w * 16 + li;               // this lane's A-operand row
  const int swA = (rA & 7) << 3;

  // ---- GEMM1: h = combined @ W0 + b0   (per wave: 16 rows x 256 cols) ----
  f32x4 acc[16];
#pragma unroll
  for (int nf = 0; nf < 16; nf++) {
    float bv = b0[nf * 16 + li];
    acc[nf] = {bv, bv, bv, bv};
  }
#pragma unroll
  for (int kk = 0; kk < 8; kk++) {
    short8 a = *(const short8*)&tile[rA][(kk * 32 + hi * 8) ^ swA];
    const ushort* wp0 = w0t + (size_t)li * 256 + kk * 32 + hi * 8;
#pragma unroll
    for (int nf = 0; nf < 16; nf++) {
      short8 b = *(const short8*)(wp0 + nf * 4096);
      acc[nf] = __builtin_amdgcn_mfma_f32_16x16x32_bf16(a, b, acc[nf], 0, 0, 0);
    }
  }

  // ---- LN1 + relu in-register; store h_ln (bf16) back into tile ----
  {
    float s[4] = {0, 0, 0, 0}, sq[4] = {0, 0, 0, 0};
#pragma unroll
    for (int nf = 0; nf < 16; nf++)
#pragma unroll
      for (int j = 0; j < 4; j++) { float v = acc[nf][j]; s[j] += v; sq[j] += v * v; }
    float mu[4], rstd[4];
#pragma unroll
    for (int j = 0; j < 4; j++) {
#pragma unroll
      for (int off = 1; off < 16; off <<= 1) {
        s[j]  += __shfl_xor(s[j], off, 64);
        sq[j] += __shfl_xor(sq[j], off, 64);
      }
      mu[j] = s[j] * (1.f / 256.f);
      float var = sq[j] * (1.f / 256.f) - mu[j] * mu[j];
      rstd[j] = rsqrtf(var + 1e-5f);
    }
#pragma unroll
    for (int nf = 0; nf < 16; nf++) {
      float gv = g0[nf * 16 + li], bev = be0[nf * 16 + li];
#pragma unroll
      for (int j = 0; j < 4; j++) {
        float v = fmaxf((acc[nf][j] - mu[j]) * rstd[j] * gv + bev, 0.f);
        int rr = w * 16 + hi * 4 + j;
        tile[rr][(nf * 16 + li) ^ ((rr & 7) << 3)] = f2bf(v);
      }
    }
  }

  // ---- nbrs similarity: 16-lane group hi computes rows hi*4..hi*4+3 ----
  float nsim_r[4];
#pragma unroll
  for (int j = 0; j < 4; j++) {
    int sidx = s0 + w * 16 + hi * 4 + j;
    int es = ssrc[sidx], ed = sdst[sidx];
    const float4* xs = (const float4*)(nbrs + (size_t)es * CC) + li * 2;
    const float4* ys = (const float4*)(nbrs + (size_t)ed * CC) + li * 2;
    float4 x0 = xs[0], y0 = ys[0], x1 = xs[1], y1 = ys[1];
    float dd = x0.x * y0.x + x0.y * y0.y + x0.z * y0.z + x0.w * y0.w
             + x1.x * y1.x + x1.y * y1.y + x1.z * y1.z + x1.w * y1.w;
#pragma unroll
    for (int off = 1; off < 16; off <<= 1) dd += __shfl_xor(dd, off, 64);
    nsim_r[j] = dd;
  }

  // ---- GEMM2: ef = h_ln @ W1 + b1   (per wave: 16 rows x 128 cols) ----
  f32x4 acc2[8];
#pragma unroll
  for (int nf = 0; nf < 8; nf++) {
    float bv = b1[nf * 16 + li];
    acc2[nf] = {bv, bv, bv, bv};
  }
#pragma unroll
  for (int kk = 0; kk < 8; kk++) {
    short8 a = *(const short8*)&tile[rA][(kk * 32 + hi * 8) ^ swA];
    const ushort* wp1 = w1t + (size_t)li * 256 + kk * 32 + hi * 8;
#pragma unroll
    for (int nf = 0; nf < 8; nf++) {
      short8 b = *(const short8*)(wp1 + nf * 4096);
      acc2[nf] = __builtin_amdgcn_mfma_f32_16x16x32_bf16(a, b, acc2[nf], 0, 0, 0);
    }
  }

  // ---- LN2 + relu + heads ----
  float pd[4], wsm[4];
  {
    float s[4] = {0, 0, 0, 0}, sq[4] = {0, 0, 0, 0};
#pragma unroll
    for (int nf = 0; nf < 8; nf++)
#pragma unroll
      for (int j = 0; j < 4; j++) { float v = acc2[nf][j]; s[j] += v; sq[j] += v * v; }
    float mu[4], rstd[4];
#pragma unroll
    for (int j = 0; j < 4; j++) {
#pragma unroll
      for (int off = 1; off < 16; off <<= 1) {
        s[j]  += __shfl_xor(s[j], off, 64);
        sq[j] += __shfl_xor(sq[j], off, 64);
      }
      mu[j] = s[j] * (1.f / 128.f);
      float var = sq[j] * (1.f / 128.f) - mu[j] * mu[j];
      rstd[j] = rsqrtf(var + 1e-5f);
      pd[j] = 0.f; wsm[j] = 0.f;
    }
#pragma unroll
    for (int nf = 0; nf < 8; nf++) {
      float gv = g1[nf * 16 + li], bev = be1[nf * 16 + li];
      float wpv = Wp[nf * 16 + li], wwv = Ww[nf * 16 + li];
#pragma unroll
      for (int j = 0; j < 4; j++) {
        float e = fmaxf((acc2[nf][j] - mu[j]) * rstd[j] * gv + bev, 0.f);
        pd[j]  += e * wpv;
        wsm[j] += e * wwv;
      }
    }
#pragma unroll
    for (int j = 0; j < 4; j++)
#pragma unroll
      for (int off = 1; off < 16; off <<= 1) {
        pd[j]  += __shfl_xor(pd[j], off, 64);
        wsm[j] += __shfl_xor(wsm[j], off, 64);
      }
  }

  float u0 = softplusf(craw[0]), u1 = softplusf(craw[1]), u2 = softplusf(craw[2]);
  float usum = u0 + u1 + u2;
  float c0 = u0 / usum, c1 = u1 / usum, c2 = u2 / usum;

  if (li == 0) {
    float sc = sscale[0], sh = sshift[0];
    float bp0 = bp[0], bw0 = bw[0], ww128 = Ww[128];
#pragma unroll
    for (int j = 0; j < 4; j++) {
      int sidx = s0 + w * 16 + hi * 4 + j;
      int es = ssrc[sidx], ed = sdst[sidx];
      float P_dec  = pd[j] + bp0;
      float P_nbr  = sc * (nsim_r[j] + sh);
      float P_cong = sc * (cong[es] + cong[ed] + sh);
      out[3 * sidx + 0] = c0 * P_dec;
      out[3 * sidx + 1] = c1 * P_nbr;
      out[3 * sidx + 2] = c2 * P_cong;
      out[3 * ESn + sidx] = fmaxf(wsm[j] + nsim_r[j] * ww128 + bw0, 0.f);
    }
  }
  if (blockIdx.x == 0 && t == 0) {
    out[4 * ESn + 0] = c0; out[4 * ESn + 1] = c1; out[4 * ESn + 2] = c2;
  }
}

} // namespace

extern "C" void kernel_launch(void* const* d_in, const int* in_sizes, int n_in,
                              void* d_out, int out_size, void* d_ws, size_t ws_size,
                              hipStream_t stream) {
  (void)in_sizes; (void)n_in; (void)out_size; (void)ws_size;
  const float* nodes  = (const float*)d_in[0];
  const float* nbrs   = (const float*)d_in[1];
  const int* sup_src  = (const int*)d_in[2];
  const int* sup_dst  = (const int*)d_in[3];
  const int* msg_src  = (const int*)d_in[4];
  const int* msg_dst  = (const int*)d_in[5];
  // d_in[6] message_edgestr: dead
  const float* W0  = (const float*)d_in[7];
  const float* b0  = (const float*)d_in[8];
  const float* g0  = (const float*)d_in[9];
  const float* be0 = (const float*)d_in[10];
  const float* W1  = (const float*)d_in[11];
  const float* b1  = (const float*)d_in[12];
  const float* g1  = (const float*)d_in[13];
  const float* be1 = (const float*)d_in[14];
  const float* Wp  = (const float*)d_in[15];
  const float* bp  = (const float*)d_in[16];
  const float* Ww  = (const float*)d_in[17];
  const float* bw  = (const float*)d_in[18];
  const float* sscale = (const float*)d_in[19];
  const float* sshift = (const float*)d_in[20];
  const float* craw   = (const float*)d_in[21];
  // d_in[22..27] mm_*: dead
  float* out = (float*)d_out;

  char* p = (char*)d_ws;
  auto take = [&](size_t bytes) -> char* {
    char* r = p; p += (bytes + 255) & ~(size_t)255; return r;
  };
  ushort* w0t  = (ushort*)take((size_t)256 * 256 * 2);
  ushort* w1t  = (ushort*)take((size_t)128 * 256 * 2);
  float*  invn = (float*)take((size_t)NN * 4);
  int*    pidx = (int*)take((size_t)NN * 4);
  float*  den  = (float*)take((size_t)NN * 4);
  float*  num  = (float*)take((size_t)NN * 4);
  float*  cnt  = (float*)take((size_t)NN * 4);
  float*  cong = (float*)take((size_t)NN * 4);

  k_init<<<(NN + 255) / 256, 256, 0, stream>>>(pidx, den, num, cnt);
  k_prep<<<96, 256, 0, stream>>>(W0, W1, w0t, w1t);
  k_norm<<<(NN + 3) / 4, 256, 0, stream>>>(nodes, invn);
  k_partner<<<(2 * ESn + 255) / 256, 256, 0, stream>>>(sup_src, sup_dst, pidx);
  k_cos16<<<EMn / 16, 256, 0, stream>>>(nodes, invn, sup_src, sup_dst, msg_src, msg_dst,
                                        pidx, den, num, cnt);
  k_cong<<<(NN + 255) / 256, 256, 0, stream>>>(den, num, cnt, cong);
  k_mlp<<<ESn / 64, 256, 0, stream>>>(nodes, nbrs, sup_src, sup_dst, cong,
                                      w0t, w1t, b0, g0, be0, b1, g1, be1,
                                      Wp, bp, Ww, bw, sscale, sshift, craw, out);
}

// Round 3
// 363.091 us; speedup vs baseline: 3.4844x; 1.6420x over previous
//
#include <hip/hip_runtime.h>
#include <math.h>

namespace {

constexpr int NN  = 50000;
constexpr int CC  = 128;
constexpr int EMn = 1000000;
constexpr int ESn = 200000;

using f32x4  = __attribute__((ext_vector_type(4))) float;
using short8 = __attribute__((ext_vector_type(8))) short;

__device__ __forceinline__ ushort f2bf(float f) {
  unsigned u = __float_as_uint(f);
  return (ushort)((u + 0x7fffu + ((u >> 16) & 1u)) >> 16);   // RNE
}
__device__ __forceinline__ float b2f(ushort u) {
  return __uint_as_float((unsigned)u << 16);
}
__device__ __forceinline__ float softplusf(float x) {
  return (x > 20.f) ? x : log1pf(expf(x));
}
__device__ __forceinline__ float wred64(float v) {
#pragma unroll
  for (int o = 32; o; o >>= 1) v += __shfl_xor(v, o, 64);
  return v;
}

// ---- K0: init scratch ----
__global__ void k_init(int* __restrict__ pidx, float* __restrict__ den,
                       float* __restrict__ num, float* __restrict__ cnt) {
  int i = blockIdx.x * blockDim.x + threadIdx.x;
  if (i < NN) { pidx[i] = -1; den[i] = 0.f; num[i] = 0.f; cnt[i] = 0.f; }
}

// ---- K_cvt: f32 -> bf16 copies of nodes and nbrs ----
__global__ void k_cvt(const float* __restrict__ nodes, const float* __restrict__ nbrs,
                      ushort* __restrict__ nodesb, ushort* __restrict__ nbrsb) {
  size_t i = (size_t)blockIdx.x * blockDim.x + threadIdx.x;
  constexpr size_t per = (size_t)NN * CC / 8;    // 800000
  if (i >= 2 * per) return;
  const float* s = (i < per) ? nodes : nbrs;
  ushort* d      = (i < per) ? nodesb : nbrsb;
  size_t off = (i < per ? i : i - per) * 8;
  float4 x0 = *(const float4*)(s + off);
  float4 x1 = *(const float4*)(s + off + 4);
  short8 v;
  v[0] = (short)f2bf(x0.x); v[1] = (short)f2bf(x0.y);
  v[2] = (short)f2bf(x0.z); v[3] = (short)f2bf(x0.w);
  v[4] = (short)f2bf(x1.x); v[5] = (short)f2bf(x1.y);
  v[6] = (short)f2bf(x1.z); v[7] = (short)f2bf(x1.w);
  *(short8*)(d + off) = v;
}

// ---- K_prep: transpose + bf16-convert W0 [256x256] and W1 [256x128] ----
__global__ void k_prep(const float* __restrict__ W0, const float* __restrict__ W1,
                       ushort* __restrict__ w0t, ushort* __restrict__ w1t) {
  __shared__ float tl[32][33];
  int b = blockIdx.x;
  const float* src; ushort* dst; int N, tk, tn;
  if (b < 64) { src = W0; dst = w0t; N = 256; tk = b >> 3; tn = b & 7; }
  else        { b -= 64; src = W1; dst = w1t; N = 128; tk = b >> 2; tn = b & 3; }
  int tx = threadIdx.x & 31, ty = threadIdx.x >> 5;
#pragma unroll
  for (int yy = 0; yy < 32; yy += 8)
    tl[ty + yy][tx] = src[(size_t)(tk * 32 + ty + yy) * N + tn * 32 + tx];
  __syncthreads();
#pragma unroll
  for (int yy = 0; yy < 32; yy += 8)
    dst[(size_t)(tn * 32 + ty + yy) * 256 + tk * 32 + tx] = f2bf(tl[tx][ty + yy]);
}

// ---- K1: inverse row norms (one wave per row, f32 nodes) ----
__global__ void k_norm(const float* __restrict__ nodes, float* __restrict__ invn) {
  int row = blockIdx.x * 4 + (threadIdx.x >> 6);
  int l = threadIdx.x & 63;
  if (row >= NN) return;
  const float* r = nodes + (size_t)row * CC;
  float a = r[l], b = r[l + 64];
  float s = wred64(a * a + b * b);
  if (l == 0) invn[row] = 1.0f / fmaxf(sqrtf(s), 1e-8f);
}

// ---- K2: partner_index scatter-max ----
__global__ void k_partner(const int* __restrict__ ss, const int* __restrict__ sd,
                          int* __restrict__ pidx) {
  int i = blockIdx.x * blockDim.x + threadIdx.x;
  if (i >= 2 * ESn) return;
  int partner = (i < ESn) ? sd[i] : ss[i - ESn];
  atomicMax(&pidx[partner], i);
}

// ---- K3: fused cos + segmented sums (16 lanes per message edge, bf16 rows) ----
__global__ void k_cos16(const ushort* __restrict__ nodesb, const float* __restrict__ invn,
                        const int* __restrict__ ss, const int* __restrict__ sd,
                        const int* __restrict__ ms, const int* __restrict__ md,
                        const int* __restrict__ pidx, float* __restrict__ den,
                        float* __restrict__ num, float* __restrict__ cnt) {
  int t = threadIdx.x;
  int e = blockIdx.x * 16 + (t >> 4);
  int li = t & 15;
  int d = md[e];
  int pi = pidx[d];
  if (pi < 0) return;                       // uniform per 16-lane group
  int q = (pi < ESn) ? ss[pi] : sd[pi - ESn];
  int s = ms[e];
  short8 x = *(const short8*)(nodesb + (size_t)q * CC + li * 8);
  short8 y = *(const short8*)(nodesb + (size_t)s * CC + li * 8);
  float dot = 0.f;
#pragma unroll
  for (int j = 0; j < 8; j++) dot += b2f((ushort)x[j]) * b2f((ushort)y[j]);
#pragma unroll
  for (int off = 1; off < 16; off <<= 1) dot += __shfl_xor(dot, off, 64);
  if (li == 0) {
    float cv = dot * invn[q] * invn[s];
    float wv = expf(10.0f * cv);
    atomicAdd(&den[q], wv);
    atomicAdd(&num[q], wv * cv);
    atomicAdd(&cnt[q], 1.0f);
  }
}

// ---- K5: cong_node ----
__global__ void k_cong(const float* __restrict__ den, const float* __restrict__ num,
                       const float* __restrict__ cnt, float* __restrict__ cong) {
  int n = blockIdx.x * blockDim.x + threadIdx.x;
  if (n >= NN) return;
  float c = cnt[n];
  cong[n] = (c > 0.f) ? (num[n] / den[n]) / c : 0.f;
}

// ---- K6: fused MFMA MLP + heads. 64 edges/block, col-split across 4 waves ----
__global__ __launch_bounds__(256) void k_mlp(
    const ushort* __restrict__ nodesb, const ushort* __restrict__ nbrsb,
    const int* __restrict__ ssrc, const int* __restrict__ sdst,
    const float* __restrict__ cong,
    const ushort* __restrict__ w0t, const ushort* __restrict__ w1t,
    const float* __restrict__ b0, const float* __restrict__ g0, const float* __restrict__ be0,
    const float* __restrict__ b1, const float* __restrict__ g1, const float* __restrict__ be1,
    const float* __restrict__ Wp, const float* __restrict__ bp,
    const float* __restrict__ Ww, const float* __restrict__ bw,
    const float* __restrict__ sscale, const float* __restrict__ sshift,
    const float* __restrict__ craw, float* __restrict__ out) {
  __shared__ ushort tile[64][256];          // combined (bf16, XOR-swizzled), reused for h_ln
  __shared__ float pstat[4][64][2];         // per-wave (s, sq) partials; reused for (pd, ws)
  __shared__ float mustd[64][2];
  __shared__ float nsimb[64];
  __shared__ int   eidx[64][2];

  const int t = threadIdx.x;
  const int w = t >> 6, l = t & 63;
  const int li = l & 15, hi = l >> 4;
  const int s0 = blockIdx.x * 64;

  if (t < 64) { eidx[t][0] = ssrc[s0 + t]; eidx[t][1] = sdst[s0 + t]; }

  // ---- stage combined = [a | m] bf16, swizzled; wave stages its 16 rows ----
  {
    int r = w * 16 + (l >> 2), q = l & 3;
    int es = ssrc[s0 + r], ed = sdst[s0 + r];
    const short8* xs = (const short8*)(nodesb + (size_t)es * CC + q * 32);
    const short8* ys = (const short8*)(nodesb + (size_t)ed * CC + q * 32);
    int sw = (r & 7) << 3;
#pragma unroll
    for (int i = 0; i < 4; i++) {
      short8 x = xs[i], y = ys[i];
      short8 av, mv;
#pragma unroll
      for (int j = 0; j < 8; j++) {
        float fx = b2f((ushort)x[j]), fy = b2f((ushort)y[j]);
        av[j] = (short)f2bf(fx + fy);
        mv[j] = (short)f2bf(fx * fy);
      }
      *(short8*)&tile[r][(q * 32 + i * 8) ^ sw] = av;
      *(short8*)&tile[r][(128 + q * 32 + i * 8) ^ sw] = mv;
    }
  }
  __syncthreads();                          // B1

  const int swl = (li & 7) << 3;
  const int n0 = w * 64;                    // GEMM1 col base for this wave

  // ---- GEMM1: h cols [n0, n0+64) for all 64 edges ----
  f32x4 acc[4][4];                          // [nf][ef]
#pragma unroll
  for (int nf = 0; nf < 4; nf++) {
    float bv = b0[n0 + nf * 16 + li];
#pragma unroll
    for (int ef = 0; ef < 4; ef++) acc[nf][ef] = {bv, bv, bv, bv};
  }
#pragma unroll
  for (int kk = 0; kk < 8; kk++) {
    short8 a[4], b[4];
#pragma unroll
    for (int ef = 0; ef < 4; ef++)
      a[ef] = *(const short8*)&tile[ef * 16 + li][(kk * 32 + hi * 8) ^ swl];
#pragma unroll
    for (int nf = 0; nf < 4; nf++)
      b[nf] = *(const short8*)(w0t + (size_t)(n0 + nf * 16 + li) * 256 + kk * 32 + hi * 8);
#pragma unroll
    for (int nf = 0; nf < 4; nf++)
#pragma unroll
      for (int ef = 0; ef < 4; ef++)
        acc[nf][ef] = __builtin_amdgcn_mfma_f32_16x16x32_bf16(a[ef], b[nf], acc[nf][ef], 0, 0, 0);
  }

  // ---- LN1 partials ----
  {
    f32x4 ps[4], qs[4];
#pragma unroll
    for (int ef = 0; ef < 4; ef++) {
      f32x4 s = acc[0][ef] + acc[1][ef] + acc[2][ef] + acc[3][ef];
      f32x4 q = acc[0][ef] * acc[0][ef] + acc[1][ef] * acc[1][ef]
              + acc[2][ef] * acc[2][ef] + acc[3][ef] * acc[3][ef];
      ps[ef] = s; qs[ef] = q;
    }
#pragma unroll
    for (int ef = 0; ef < 4; ef++)
#pragma unroll
      for (int j = 0; j < 4; j++)
#pragma unroll
        for (int off = 1; off < 16; off <<= 1) {
          ps[ef][j] += __shfl_xor(ps[ef][j], off, 64);
          qs[ef][j] += __shfl_xor(qs[ef][j], off, 64);
        }
    if (li < 4) {
#pragma unroll
      for (int ef = 0; ef < 4; ef++) {
        int r = ef * 16 + hi * 4 + li;
        pstat[w][r][0] = ps[ef][li];
        pstat[w][r][1] = qs[ef][li];
      }
    }
  }
  __syncthreads();                          // B2
  if (t < 64) {
    float s = 0.f, sq = 0.f;
#pragma unroll
    for (int ww = 0; ww < 4; ww++) { s += pstat[ww][t][0]; sq += pstat[ww][t][1]; }
    float mu = s * (1.f / 256.f);
    float var = sq * (1.f / 256.f) - mu * mu;
    mustd[t][0] = mu; mustd[t][1] = rsqrtf(var + 1e-5f);
  }

  // ---- nbrs similarity (edge-split: wave w -> edges [16w,16w+16), 4 lanes/edge) ----
  {
    int e = w * 16 + (l >> 2), q4 = l & 3;
    int es = eidx[e][0], ed = eidx[e][1];
    const short8* xs = (const short8*)(nbrsb + (size_t)es * CC + q4 * 32);
    const short8* ys = (const short8*)(nbrsb + (size_t)ed * CC + q4 * 32);
    float dd = 0.f;
#pragma unroll
    for (int i = 0; i < 4; i++) {
      short8 x = xs[i], y = ys[i];
#pragma unroll
      for (int j = 0; j < 8; j++) dd += b2f((ushort)x[j]) * b2f((ushort)y[j]);
    }
    dd += __shfl_xor(dd, 1, 64);
    dd += __shfl_xor(dd, 2, 64);
    if (q4 == 0) nsimb[e] = dd;
  }
  __syncthreads();                          // B3

  // ---- LN1 normalize + relu -> tile (h_ln) ----
  {
    float mu[4][4], rs[4][4];
#pragma unroll
    for (int ef = 0; ef < 4; ef++)
#pragma unroll
      for (int j = 0; j < 4; j++) {
        int r = ef * 16 + hi * 4 + j;
        mu[ef][j] = mustd[r][0]; rs[ef][j] = mustd[r][1];
      }
#pragma unroll
    for (int nf = 0; nf < 4; nf++) {
      int col = n0 + nf * 16 + li;
      float gv = g0[col], bev = be0[col];
#pragma unroll
      for (int ef = 0; ef < 4; ef++)
#pragma unroll
        for (int j = 0; j < 4; j++) {
          int r = ef * 16 + hi * 4 + j;
          float v = fmaxf((acc[nf][ef][j] - mu[ef][j]) * rs[ef][j] * gv + bev, 0.f);
          tile[r][col ^ ((r & 7) << 3)] = f2bf(v);
        }
    }
  }
  __syncthreads();                          // B4

  // ---- GEMM2: ef cols [32w, 32w+32) for all 64 edges ----
  const int n2 = w * 32;
  f32x4 acc2[2][4];
#pragma unroll
  for (int nf = 0; nf < 2; nf++) {
    float bv = b1[n2 + nf * 16 + li];
#pragma unroll
    for (int ef = 0; ef < 4; ef++) acc2[nf][ef] = {bv, bv, bv, bv};
  }
#pragma unroll
  for (int kk = 0; kk < 8; kk++) {
    short8 a[4], b[2];
#pragma unroll
    for (int ef = 0; ef < 4; ef++)
      a[ef] = *(const short8*)&tile[ef * 16 + li][(kk * 32 + hi * 8) ^ swl];
#pragma unroll
    for (int nf = 0; nf < 2; nf++)
      b[nf] = *(const short8*)(w1t + (size_t)(n2 + nf * 16 + li) * 256 + kk * 32 + hi * 8);
#pragma unroll
    for (int nf = 0; nf < 2; nf++)
#pragma unroll
      for (int ef = 0; ef < 4; ef++)
        acc2[nf][ef] = __builtin_amdgcn_mfma_f32_16x16x32_bf16(a[ef], b[nf], acc2[nf][ef], 0, 0, 0);
  }

  // ---- LN2 partials ----
  {
    f32x4 ps[4], qs[4];
#pragma unroll
    for (int ef = 0; ef < 4; ef++) {
      ps[ef] = acc2[0][ef] + acc2[1][ef];
      qs[ef] = acc2[0][ef] * acc2[0][ef] + acc2[1][ef] * acc2[1][ef];
    }
#pragma unroll
    for (int ef = 0; ef < 4; ef++)
#pragma unroll
      for (int j = 0; j < 4; j++)
#pragma unroll
        for (int off = 1; off < 16; off <<= 1) {
          ps[ef][j] += __shfl_xor(ps[ef][j], off, 64);
          qs[ef][j] += __shfl_xor(qs[ef][j], off, 64);
        }
    if (li < 4) {
#pragma unroll
      for (int ef = 0; ef < 4; ef++) {
        int r = ef * 16 + hi * 4 + li;
        pstat[w][r][0] = ps[ef][li];
        pstat[w][r][1] = qs[ef][li];
      }
    }
  }
  __syncthreads();                          // B5
  if (t < 64) {
    float s = 0.f, sq = 0.f;
#pragma unroll
    for (int ww = 0; ww < 4; ww++) { s += pstat[ww][t][0]; sq += pstat[ww][t][1]; }
    float mu = s * (1.f / 128.f);
    float var = sq * (1.f / 128.f) - mu * mu;
    mustd[t][0] = mu; mustd[t][1] = rsqrtf(var + 1e-5f);
  }
  __syncthreads();                          // B6

  // ---- LN2 normalize + relu + head partial dots ----
  {
    float mu[4][4], rs[4][4];
#pragma unroll
    for (int ef = 0; ef < 4; ef++)
#pragma unroll
      for (int j = 0; j < 4; j++) {
        int r = ef * 16 + hi * 4 + j;
        mu[ef][j] = mustd[r][0]; rs[ef][j] = mustd[r][1];
      }
    f32x4 pdp[4] = {{0,0,0,0},{0,0,0,0},{0,0,0,0},{0,0,0,0}};
    f32x4 wsp[4] = {{0,0,0,0},{0,0,0,0},{0,0,0,0},{0,0,0,0}};
#pragma unroll
    for (int nf = 0; nf < 2; nf++) {
      int col = n2 + nf * 16 + li;
      float gv = g1[col], bev = be1[col];
      float wpv = Wp[col], wwv = Ww[col];
#pragma unroll
      for (int ef = 0; ef < 4; ef++)
#pragma unroll
        for (int j = 0; j < 4; j++) {
          float e = fmaxf((acc2[nf][ef][j] - mu[ef][j]) * rs[ef][j] * gv + bev, 0.f);
          pdp[ef][j] += e * wpv;
          wsp[ef][j] += e * wwv;
        }
    }
#pragma unroll
    for (int ef = 0; ef < 4; ef++)
#pragma unroll
      for (int j = 0; j < 4; j++)
#pragma unroll
        for (int off = 1; off < 16; off <<= 1) {
          pdp[ef][j] += __shfl_xor(pdp[ef][j], off, 64);
          wsp[ef][j] += __shfl_xor(wsp[ef][j], off, 64);
        }
    if (li < 4) {
#pragma unroll
      for (int ef = 0; ef < 4; ef++) {
        int r = ef * 16 + hi * 4 + li;
        pstat[w][r][0] = pdp[ef][li];
        pstat[w][r][1] = wsp[ef][li];
      }
    }
  }
  __syncthreads();                          // B7

  if (t < 64) {
    float pd = 0.f, ws = 0.f;
#pragma unroll
    for (int ww = 0; ww < 4; ww++) { pd += pstat[ww][t][0]; ws += pstat[ww][t][1]; }
    float nsim = nsimb[t];
    int es = eidx[t][0], ed = eidx[t][1];
    float u0 = softplusf(craw[0]), u1 = softplusf(craw[1]), u2 = softplusf(craw[2]);
    float usum = u0 + u1 + u2;
    float c0 = u0 / usum, c1 = u1 / usum, c2 = u2 / usum;
    float sc = sscale[0], sh = sshift[0];
    int sidx = s0 + t;
    out[3 * sidx + 0] = c0 * (pd + bp[0]);
    out[3 * sidx + 1] = c1 * (sc * (nsim + sh));
    out[3 * sidx + 2] = c2 * (sc * (cong[es] + cong[ed] + sh));
    out[3 * ESn + sidx] = fmaxf(ws + nsim * Ww[128] + bw[0], 0.f);
    if (blockIdx.x == 0 && t == 0) {
      out[4 * ESn + 0] = c0; out[4 * ESn + 1] = c1; out[4 * ESn + 2] = c2;
    }
  }
}

} // namespace

extern "C" void kernel_launch(void* const* d_in, const int* in_sizes, int n_in,
                              void* d_out, int out_size, void* d_ws, size_t ws_size,
                              hipStream_t stream) {
  (void)in_sizes; (void)n_in; (void)out_size; (void)ws_size;
  const float* nodes  = (const float*)d_in[0];
  const float* nbrs   = (const float*)d_in[1];
  const int* sup_src  = (const int*)d_in[2];
  const int* sup_dst  = (const int*)d_in[3];
  const int* msg_src  = (const int*)d_in[4];
  const int* msg_dst  = (const int*)d_in[5];
  // d_in[6] message_edgestr: dead
  const float* W0  = (const float*)d_in[7];
  const float* b0  = (const float*)d_in[8];
  const float* g0  = (const float*)d_in[9];
  const float* be0 = (const float*)d_in[10];
  const float* W1  = (const float*)d_in[11];
  const float* b1  = (const float*)d_in[12];
  const float* g1  = (const float*)d_in[13];
  const float* be1 = (const float*)d_in[14];
  const float* Wp  = (const float*)d_in[15];
  const float* bp  = (const float*)d_in[16];
  const float* Ww  = (const float*)d_in[17];
  const float* bw  = (const float*)d_in[18];
  const float* sscale = (const float*)d_in[19];
  const float* sshift = (const float*)d_in[20];
  const float* craw   = (const float*)d_in[21];
  // d_in[22..27] mm_*: dead
  float* out = (float*)d_out;

  char* p = (char*)d_ws;
  auto take = [&](size_t bytes) -> char* {
    char* r = p; p += (bytes + 255) & ~(size_t)255; return r;
  };
  ushort* w0t    = (ushort*)take((size_t)256 * 256 * 2);
  ushort* w1t    = (ushort*)take((size_t)128 * 256 * 2);
  ushort* nodesb = (ushort*)take((size_t)NN * CC * 2);
  ushort* nbrsb  = (ushort*)take((size_t)NN * CC * 2);
  float*  invn   = (float*)take((size_t)NN * 4);
  int*    pidx   = (int*)take((size_t)NN * 4);
  float*  den    = (float*)take((size_t)NN * 4);
  float*  num    = (float*)take((size_t)NN * 4);
  float*  cnt    = (float*)take((size_t)NN * 4);
  float*  cong   = (float*)take((size_t)NN * 4);

  k_init<<<(NN + 255) / 256, 256, 0, stream>>>(pidx, den, num, cnt);
  k_cvt<<<(2 * NN * CC / 8 + 255) / 256, 256, 0, stream>>>(nodes, nbrs, nodesb, nbrsb);
  k_prep<<<96, 256, 0, stream>>>(W0, W1, w0t, w1t);
  k_norm<<<(NN + 3) / 4, 256, 0, stream>>>(nodes, invn);
  k_partner<<<(2 * ESn + 255) / 256, 256, 0, stream>>>(sup_src, sup_dst, pidx);
  k_cos16<<<EMn / 16, 256, 0, stream>>>(nodesb, invn, sup_src, sup_dst, msg_src, msg_dst,
                                        pidx, den, num, cnt);
  k_cong<<<(NN + 255) / 256, 256, 0, stream>>>(den, num, cnt, cong);
  k_mlp<<<ESn / 64, 256, 0, stream>>>(nodesb, nbrsb, sup_src, sup_dst, cong,
                                      w0t, w1t, b0, g0, be0, b1, g1, be1,
                                      Wp, bp, Ww, bw, sscale, sshift, craw, out);
}